// Round 5
// baseline (430.400 us; speedup 1.0000x reference)
//
#include <hip/hip_runtime.h>
#include <math.h>

// Problem constants
#define Bc   4
#define Hc   64
#define Wc   64
#define Dc   384
#define Nc   4096      // H*W
#define Mc   12
#define Pc   9
#define DHc  32
#define DFFc 1152
#define BNc  (Bc*Nc)   // 16384

typedef __attribute__((ext_vector_type(8))) short short8;
typedef __attribute__((ext_vector_type(4))) float floatx4;

__device__ __forceinline__ ushort f2bf(float f) {
    union { float f; unsigned u; } v; v.f = f;
    unsigned r = v.u + 0x7fffu + ((v.u >> 16) & 1u);   // RNE
    return (ushort)(r >> 16);
}

// ---------------------------------------------------------------------------
// K0: cumsum of not_mask along H (cum_y) and W (cum_x)
// ---------------------------------------------------------------------------
__global__ void cumsum_mask_kernel(const float* __restrict__ qmask,
                                   float* __restrict__ cum_y,
                                   float* __restrict__ cum_x) {
    int t = blockIdx.x * blockDim.x + threadIdx.x;
    if (t < Bc * Wc) {
        int b = t / Wc, w = t % Wc;
        float run = 0.f;
        for (int h = 0; h < Hc; ++h) {
            float nm = (qmask[(b * Hc + h) * Wc + w] == 255.0f) ? 0.f : 1.f;
            run += nm;
            cum_y[(b * Hc + h) * Wc + w] = run;
        }
    } else if (t < Bc * Wc + Bc * Hc) {
        int t2 = t - Bc * Wc;
        int b = t2 / Hc, h = t2 % Hc;
        float run = 0.f;
        for (int w = 0; w < Wc; ++w) {
            float nm = (qmask[(b * Hc + h) * Wc + w] == 255.0f) ? 0.f : 1.f;
            run += nm;
            cum_x[(b * Hc + h) * Wc + w] = run;
        }
    }
}

// ---------------------------------------------------------------------------
// K1: transpose x[B,D,N] -> src_f[B,N,D] (fp32) + src_bf (bf16);
//     qpos_bf = bf16(src + sine_pos + level_embed). Fast-math trig.
// ---------------------------------------------------------------------------
__global__ void transpose_pos_kernel(const float* __restrict__ x,
                                     const float* __restrict__ cum_y,
                                     const float* __restrict__ cum_x,
                                     const float* __restrict__ level_embed,
                                     float* __restrict__ src_f,
                                     ushort* __restrict__ src_bf,
                                     ushort* __restrict__ qpos_bf) {
    __shared__ float tile[32][33];
    int b  = blockIdx.z;
    int n0 = blockIdx.x * 32, d0 = blockIdx.y * 32;
    int tx = threadIdx.x, ty = threadIdx.y;
    tile[ty][tx] = x[((size_t)b * Dc + (d0 + ty)) * Nc + (n0 + tx)];
    __syncthreads();
    int n = n0 + ty, d = d0 + tx;
    float v = tile[tx][ty];
    size_t oi = ((size_t)b * Nc + n) * Dc + d;
    src_f[oi]  = v;
    src_bf[oi] = f2bf(v);
    int h = n >> 6, w = n & 63;
    const float TWO_PI = 6.28318530717958647692f;
    float vy = cum_y[(b * Hc + h) * Wc + w] /
               (cum_y[(b * Hc + (Hc - 1)) * Wc + w] + 1e-6f) * TWO_PI;
    float vx = cum_x[(b * Hc + h) * Wc + w] /
               (cum_x[(b * Hc + h) * Wc + (Wc - 1)] + 1e-6f) * TWO_PI;
    int   i  = (d < 192) ? d : d - 192;
    float vv = (d < 192) ? vy : vx;
    float e   = (float)(i >> 1) * (2.0f / 192.0f);
    float idt = exp2f(e * -13.28771237954945f);
    float ang = vv * idt;
    float pe  = (i & 1) ? __cosf(ang) : __sinf(ang);
    qpos_bf[oi] = f2bf(v + pe + level_embed[d]);
}

// ---------------------------------------------------------------------------
// K1b: convert all weight matrices fp32 -> bf16; concat so/aw biases (fp32)
// ---------------------------------------------------------------------------
#define SOW_N  82944     // 216*384
#define AWW_N  41472     // 108*384
#define VPW_N  147456    // 384*384
#define OPW_N  147456
#define W1_N   442368    // 1152*384
#define W2_N   442368    // 384*1152
#define WTOT   1304064

__global__ void convert_weights_kernel(const float* __restrict__ so_w,
                                       const float* __restrict__ aw_w,
                                       const float* __restrict__ vp_w,
                                       const float* __restrict__ op_w,
                                       const float* __restrict__ w1,
                                       const float* __restrict__ w2,
                                       const float* __restrict__ so_b,
                                       const float* __restrict__ aw_b,
                                       ushort* __restrict__ out,
                                       float* __restrict__ bias_out) {
    int i = blockIdx.x * 256 + threadIdx.x;
    if (i >= WTOT) {
        int j = i - WTOT;
        if (j < 324) bias_out[j] = (j < 216) ? so_b[j] : aw_b[j - 216];
        return;
    }
    float v;
    int j = i;
    if (j < SOW_N) v = so_w[j];
    else if ((j -= SOW_N) < AWW_N) v = aw_w[j];
    else if ((j -= AWW_N) < VPW_N) v = vp_w[j];
    else if ((j -= VPW_N) < OPW_N) v = op_w[j];
    else if ((j -= OPW_N) < W1_N)  v = w1[j];
    else { j -= W1_N; v = w2[j]; }
    out[i] = f2bf(v);
}

// ---------------------------------------------------------------------------
// K2: register-direct bf16 MFMA GEMM (no LDS, no barriers).
//     C[16384,Nout] = A[16384,K] * Wt[Nout,K]^T (+bias)(+relu)(+rowmask)
//     Both A and B fragments are 16B-contiguous in the row-major operands ->
//     global_load_dwordx4 straight to registers; the weight matrix slice per
//     wave (<=144KB) stays L1/L2-resident. K-loop is pure load<->mfma with
//     compiler-scheduled vmcnt - no barrier drain (the R4 bottleneck).
//     KT must be a multiple of 384; 12-step inner loop fully unrolls.
//     Weight over-reads past Nout stay inside wbuf; epilogue guards col.
// ---------------------------------------------------------------------------
template <int KT>
__global__ __launch_bounds__(256) void gemm_bf16_reg_kernel(
        const ushort* __restrict__ A, const ushort* __restrict__ Wt,
        const float* __restrict__ bias,
        float* __restrict__ Cf, ushort* __restrict__ Cb,
        int Nout, int relu, const float* __restrict__ qmask) {
    const int tid  = threadIdx.x;
    const int m0   = blockIdx.y * 128;
    const int n0   = blockIdx.x * 128;
    const int lane = tid & 63;
    const int wv   = tid >> 6;
    const int wr   = (wv >> 1) * 64;   // wave row offset
    const int wc   = (wv & 1) * 64;    // wave col offset
    const int quad = lane >> 4;
    const int lrow = lane & 15;

    // A-operand layout (16x16x32): lane holds A[m = lrow][k = quad*8 .. +8)
    const ushort* Ab = A  + (size_t)(m0 + wr + lrow) * KT + quad * 8;
    const ushort* Bb = Wt + (size_t)(n0 + wc + lrow) * KT + quad * 8;

    floatx4 acc[4][4];
    #pragma unroll
    for (int i = 0; i < 4; ++i)
        #pragma unroll
        for (int j = 0; j < 4; ++j)
            acc[i][j] = (floatx4)(0.f);

    for (int kc = 0; kc < KT; kc += 384) {
        #pragma unroll
        for (int kk = 0; kk < 12; ++kk) {
            const int k0 = kc + kk * 32;
            short8 afr[4], bfr[4];
            #pragma unroll
            for (int i = 0; i < 4; ++i)
                afr[i] = *(const short8*)(Ab + (size_t)(i * 16) * KT + k0);
            #pragma unroll
            for (int j = 0; j < 4; ++j)
                bfr[j] = *(const short8*)(Bb + (size_t)(j * 16) * KT + k0);
            #pragma unroll
            for (int i = 0; i < 4; ++i)
                #pragma unroll
                for (int j = 0; j < 4; ++j)
                    acc[i][j] = __builtin_amdgcn_mfma_f32_16x16x32_bf16(
                        afr[i], bfr[j], acc[i][j], 0, 0, 0);
        }
    }

    // row-mask multipliers (value projection only)
    float mz[4][4];
    #pragma unroll
    for (int i = 0; i < 4; ++i)
        #pragma unroll
        for (int r = 0; r < 4; ++r) {
            int row = m0 + wr + i * 16 + quad * 4 + r;
            mz[i][r] = (qmask && qmask[row] == 255.0f) ? 0.f : 1.f;
        }

    // C/D layout (16x16x32): col = lane&15, row = quad*4 + reg
    #pragma unroll
    for (int i = 0; i < 4; ++i) {
        #pragma unroll
        for (int j = 0; j < 4; ++j) {
            int col = n0 + wc + j * 16 + lrow;
            if (col >= Nout) continue;
            float bsv = bias ? bias[col] : 0.f;
            #pragma unroll
            for (int r = 0; r < 4; ++r) {
                int row = m0 + wr + i * 16 + quad * 4 + r;
                float v = acc[i][j][r] + bsv;
                if (relu) v = fmaxf(v, 0.f);
                v *= mz[i][r];
                if (Cf) Cf[(size_t)row * Nout + col] = v;
                if (Cb) Cb[(size_t)row * Nout + col] = f2bf(v);
            }
        }
    }
}

// ---------------------------------------------------------------------------
// K3: softmax over P=9 per (b,n,m) from soaw[:,216+m*9..], pack to 12 floats
// ---------------------------------------------------------------------------
__global__ void softmax_pack_kernel(const float* __restrict__ soaw,
                                    float* __restrict__ pack) {
    int idx = blockIdx.x * 256 + threadIdx.x;     // bn*M + m
    if (idx >= BNc * Mc) return;
    int m  = idx % Mc;
    int bn = idx / Mc;
    const float* l = soaw + (size_t)bn * 324 + 216 + m * Pc;
    float e[Pc];
    float mx = l[0];
    #pragma unroll
    for (int i = 1; i < Pc; ++i) mx = fmaxf(mx, l[i]);
    float s = 0.f;
    #pragma unroll
    for (int i = 0; i < Pc; ++i) { e[i] = __expf(l[i] - mx); s += e[i]; }
    float inv = 1.f / s;
    float* o = pack + (size_t)idx * 12;
    #pragma unroll
    for (int i = 0; i < Pc; ++i) o[i] = e[i] * inv;
    o[9] = 0.f; o[10] = 0.f; o[11] = 0.f;
}

// ---------------------------------------------------------------------------
// K4: deformable attention gather v3.
//     4-lane group per (b,n,m); lane = 8 channels (bf16x8 = 16B loads).
// ---------------------------------------------------------------------------
__global__ __launch_bounds__(256) void deform_attn_kernel(
        const ushort* __restrict__ value_bf, const float* __restrict__ soaw,
        const float* __restrict__ pack, ushort* __restrict__ out) {
    int gid = blockIdx.x * 64 + (threadIdx.x >> 2);   // (b*N+n)*M + m
    int l4  = threadIdx.x & 3;                        // channel octet
    int m  = gid % Mc;
    int bn = gid / Mc;
    int b  = bn >> 12;
    int n  = bn & 4095;
    int h  = n >> 6, w = n & 63;
    const float* sop = soaw + (size_t)bn * 324 + m * 18;
    const float* awp = pack + (size_t)gid * 12;
    float4 aw0 = *(const float4*)(awp);
    float4 aw1 = *(const float4*)(awp + 4);
    float  aw8 = awp[8];
    float awv[Pc] = {aw0.x, aw0.y, aw0.z, aw0.w, aw1.x, aw1.y, aw1.z, aw1.w, aw8};
    const ushort* vb = value_bf + ((size_t)b * Nc) * Dc + m * DHc + l4 * 8;
    float acc[8] = {0.f, 0.f, 0.f, 0.f, 0.f, 0.f, 0.f, 0.f};
    #pragma unroll
    for (int p = 0; p < Pc; ++p) {
        float2 so2 = *(const float2*)(sop + p * 2);
        float px = (float)w + so2.x;
        float py = (float)h + so2.y;
        float x0f = floorf(px), y0f = floorf(py);
        float lx = px - x0f, ly = py - y0f;
        int x0 = (int)x0f, y0 = (int)y0f;
        int x1 = x0 + 1,  y1 = y0 + 1;
        float a = awv[p];
        float w00 = (1.f - lx) * (1.f - ly) * a;
        float w01 = lx * (1.f - ly) * a;
        float w10 = (1.f - lx) * ly * a;
        float w11 = lx * ly * a;
        bool bx0 = (unsigned)x0 < 64u, bx1 = (unsigned)x1 < 64u;
        bool by0 = (unsigned)y0 < 64u, by1 = (unsigned)y1 < 64u;
        w00 = (bx0 && by0) ? w00 : 0.f;
        w01 = (bx1 && by0) ? w01 : 0.f;
        w10 = (bx0 && by1) ? w10 : 0.f;
        w11 = (bx1 && by1) ? w11 : 0.f;
        int cx0 = min(max(x0, 0), 63), cx1 = min(max(x1, 0), 63);
        int cy0 = min(max(y0, 0), 63), cy1 = min(max(y1, 0), 63);
        uint4 q00 = *(const uint4*)(vb + (size_t)(cy0 * 64 + cx0) * Dc);
        uint4 q01 = *(const uint4*)(vb + (size_t)(cy0 * 64 + cx1) * Dc);
        uint4 q10 = *(const uint4*)(vb + (size_t)(cy1 * 64 + cx0) * Dc);
        uint4 q11 = *(const uint4*)(vb + (size_t)(cy1 * 64 + cx1) * Dc);
        union { unsigned u; float f; } t;
        #define ACC2(word, wg, k)                                   \
            t.u = (word) << 16;         acc[k]     += (wg) * t.f;   \
            t.u = (word) & 0xffff0000u; acc[k + 1] += (wg) * t.f;
        #define ACC8(q, wg) \
            ACC2((q).x, wg, 0) ACC2((q).y, wg, 2) ACC2((q).z, wg, 4) ACC2((q).w, wg, 6)
        ACC8(q00, w00) ACC8(q01, w01) ACC8(q10, w10) ACC8(q11, w11)
        #undef ACC8
        #undef ACC2
    }
    short8 o;
    #pragma unroll
    for (int k = 0; k < 8; ++k) o[k] = (short)f2bf(acc[k]);
    *(short8*)(out + (size_t)bn * Dc + m * DHc + l4 * 8) = o;
}

// ---------------------------------------------------------------------------
// K5: out = LayerNorm(a + r) * g + beta ; optional bf16 copy. In-place safe.
// ---------------------------------------------------------------------------
__global__ __launch_bounds__(128) void ln_residual_kernel(
        const float* a, const float* r,
        const float* g, const float* beta,
        float* out, ushort* outb) {
    int row = blockIdx.x;
    int tid = threadIdx.x;
    float4 v = make_float4(0.f, 0.f, 0.f, 0.f);
    if (tid < 96) {
        float4 av = ((const float4*)(a + (size_t)row * Dc))[tid];
        float4 rv = ((const float4*)(r + (size_t)row * Dc))[tid];
        v.x = av.x + rv.x; v.y = av.y + rv.y;
        v.z = av.z + rv.z; v.w = av.w + rv.w;
    }
    float s1 = v.x + v.y + v.z + v.w;
    float s2 = v.x * v.x + v.y * v.y + v.z * v.z + v.w * v.w;
    __shared__ float sh1[128], sh2[128];
    sh1[tid] = s1; sh2[tid] = s2;
    __syncthreads();
    for (int off = 64; off > 0; off >>= 1) {
        if (tid < off) { sh1[tid] += sh1[tid + off]; sh2[tid] += sh2[tid + off]; }
        __syncthreads();
    }
    float mu  = sh1[0] * (1.0f / Dc);
    float var = sh2[0] * (1.0f / Dc) - mu * mu;
    float rs  = rsqrtf(var + 1e-5f);
    if (tid < 96) {
        float4 gv = ((const float4*)g)[tid];
        float4 bv = ((const float4*)beta)[tid];
        float4 o;
        o.x = (v.x - mu) * rs * gv.x + bv.x;
        o.y = (v.y - mu) * rs * gv.y + bv.y;
        o.z = (v.z - mu) * rs * gv.z + bv.z;
        o.w = (v.w - mu) * rs * gv.w + bv.w;
        ((float4*)(out + (size_t)row * Dc))[tid] = o;
        if (outb) {
            ushort4 ob;
            ob.x = f2bf(o.x); ob.y = f2bf(o.y);
            ob.z = f2bf(o.z); ob.w = f2bf(o.w);
            ((ushort4*)(outb + (size_t)row * Dc))[tid] = ob;
        }
    }
}

// ---------------------------------------------------------------------------
// K6: transpose src[B,N,D] -> out[B,D,N]
// ---------------------------------------------------------------------------
__global__ void transpose_out_kernel(const float* __restrict__ src,
                                     float* __restrict__ out) {
    __shared__ float tile[32][33];
    int b  = blockIdx.z;
    int n0 = blockIdx.x * 32, d0 = blockIdx.y * 32;
    int tx = threadIdx.x, ty = threadIdx.y;
    tile[ty][tx] = src[((size_t)b * Nc + (n0 + ty)) * Dc + (d0 + tx)];
    __syncthreads();
    out[((size_t)b * Dc + (d0 + ty)) * Nc + (n0 + tx)] = tile[tx][ty];
}

// ---------------------------------------------------------------------------
extern "C" void kernel_launch(void* const* d_in, const int* in_sizes, int n_in,
                              void* d_out, int out_size, void* d_ws, size_t ws_size,
                              hipStream_t stream) {
    (void)in_sizes; (void)n_in; (void)out_size; (void)ws_size;
    const float* x      = (const float*)d_in[0];
    const float* qmask  = (const float*)d_in[1];
    const float* so_w   = (const float*)d_in[2];
    const float* so_b   = (const float*)d_in[3];
    const float* aw_w   = (const float*)d_in[4];
    const float* aw_b   = (const float*)d_in[5];
    const float* vp_w   = (const float*)d_in[6];
    const float* vp_b   = (const float*)d_in[7];
    const float* op_w   = (const float*)d_in[8];
    const float* op_b   = (const float*)d_in[9];
    const float* ln1_g  = (const float*)d_in[10];
    const float* ln1_b  = (const float*)d_in[11];
    const float* w1     = (const float*)d_in[12];
    const float* w2     = (const float*)d_in[13];
    const float* ln2_g  = (const float*)d_in[14];
    const float* ln2_b  = (const float*)d_in[15];
    const float* lvl    = (const float*)d_in[16];
    float* out = (float*)d_out;

    // Workspace layout (~129 MB in floats):
    float*  ws       = (float*)d_ws;
    float*  src_f    = ws;                          // 6291456 f (residual/q1/q2)
    float*  proj_f   = src_f + 6291456;             // 6291456 f (op out, FFN2 out)
    ushort* src_bf   = (ushort*)(proj_f + 6291456); // 6291456 us
    ushort* qpos_bf  = src_bf + 6291456;            // 6291456 us (qpos->attn->q1_bf)
    ushort* value_bf = qpos_bf + 6291456;           // 6291456 us
    ushort* hbuf_bf  = value_bf + 6291456;          // 18874368 us (FFN hidden)
    float*  soaw_f   = (float*)hbuf_bf;             // 5308416 f overlay (dead pre-FFN1)
    float*  pack_f   = soaw_f + 5308416;            // 2359296 f overlay (dead pre-FFN1)
    ushort* wbuf     = hbuf_bf + 18874368;          // 1304064 us
    float*  soaw_bias= (float*)(wbuf + 1304064);    // 324 f
    float*  cum_y    = soaw_bias + 324;             // 16384 f
    float*  cum_x    = cum_y + 16384;               // 16384 f

    const ushort* soaw_wb = wbuf;                   // [324,384] (so_w ++ aw_w)
    const ushort* vp_wb = soaw_wb + SOW_N + AWW_N;
    const ushort* op_wb = vp_wb + VPW_N;
    const ushort* w1_b  = op_wb + OPW_N;
    const ushort* w2_b  = w1_b + W1_N;

    // 0) mask cumsums + weight conversion (+bias concat)
    cumsum_mask_kernel<<<2, 256, 0, stream>>>(qmask, cum_y, cum_x);
    convert_weights_kernel<<<(WTOT + 324 + 255) / 256, 256, 0, stream>>>(
        so_w, aw_w, vp_w, op_w, w1, w2, so_b, aw_b, wbuf, soaw_bias);
    // 1) transpose + pos encode
    transpose_pos_kernel<<<dim3(Nc / 32, Dc / 32, Bc), dim3(32, 32), 0, stream>>>(
        x, cum_y, cum_x, lvl, src_f, src_bf, qpos_bf);
    // 2) merged sampling-offset + attn-weight projection; value projection
    gemm_bf16_reg_kernel<384><<<dim3(3, BNc / 128), 256, 0, stream>>>(
        qpos_bf, soaw_wb, soaw_bias, soaw_f, nullptr, 324, 0, nullptr);
    gemm_bf16_reg_kernel<384><<<dim3(3, BNc / 128), 256, 0, stream>>>(
        src_bf, vp_wb, vp_b, nullptr, value_bf, Dc, 0, qmask);
    // 3) softmax + pack attention weights
    softmax_pack_kernel<<<(BNc * Mc + 255) / 256, 256, 0, stream>>>(soaw_f, pack_f);
    // 4) deformable gather -> attn_bf (into qpos_bf region; qpos dead)
    deform_attn_kernel<<<(BNc * Mc) / 64, 256, 0, stream>>>(
        value_bf, soaw_f, pack_f, qpos_bf);
    // 5) output projection
    gemm_bf16_reg_kernel<384><<<dim3(3, BNc / 128), 256, 0, stream>>>(
        qpos_bf, op_wb, op_b, proj_f, nullptr, Dc, 0, nullptr);
    // 6) q1 = LN(src + attnproj) — in place, bf16 copy to qpos_bf
    ln_residual_kernel<<<BNc, 128, 0, stream>>>(
        src_f, proj_f, ln1_g, ln1_b, src_f, qpos_bf);
    // 7) FFN
    gemm_bf16_reg_kernel<384><<<dim3(9, BNc / 128), 256, 0, stream>>>(
        qpos_bf, w1_b, nullptr, nullptr, hbuf_bf, DFFc, 1, nullptr);
    gemm_bf16_reg_kernel<1152><<<dim3(3, BNc / 128), 256, 0, stream>>>(
        hbuf_bf, w2_b, nullptr, proj_f, nullptr, Dc, 0, nullptr);
    // 8) q2 = LN(q1 + ffn2) — in place
    ln_residual_kernel<<<BNc, 128, 0, stream>>>(
        src_f, proj_f, ln2_g, ln2_b, src_f, nullptr);
    // 9) transpose to [B,D,H,W]
    transpose_out_kernel<<<dim3(Nc / 32, Dc / 32, Bc), dim3(32, 32), 0, stream>>>(
        src_f, out);
}

// Round 6
// 360.972 us; speedup vs baseline: 1.1923x; 1.1923x over previous
//
#include <hip/hip_runtime.h>
#include <math.h>

// Problem constants
#define Bc   4
#define Hc   64
#define Wc   64
#define Dc   384
#define Nc   4096      // H*W
#define Mc   12
#define Pc   9
#define DHc  32
#define DFFc 1152
#define BNc  (Bc*Nc)   // 16384

typedef __attribute__((ext_vector_type(8))) short short8;
typedef __attribute__((ext_vector_type(4))) float floatx4;

__device__ __forceinline__ ushort f2bf(float f) {
    union { float f; unsigned u; } v; v.f = f;
    unsigned r = v.u + 0x7fffu + ((v.u >> 16) & 1u);   // RNE
    return (ushort)(r >> 16);
}

__device__ __forceinline__ void gload_lds16(const void* g, void* l) {
    __builtin_amdgcn_global_load_lds(
        (const __attribute__((address_space(1))) void*)(uintptr_t)g,
        (__attribute__((address_space(3))) void*)(uintptr_t)l,
        16, 0, 0);
}

// ---------------------------------------------------------------------------
// K0: fused init — weight fp32->bf16 convert, bias concat, mask cumsums
// ---------------------------------------------------------------------------
#define SOW_N  82944     // 216*384
#define AWW_N  41472     // 108*384
#define VPW_N  147456    // 384*384
#define OPW_N  147456
#define W1_N   442368    // 1152*384
#define W2_N   442368    // 384*1152
#define WTOT   1304064

__global__ void init_kernel(const float* __restrict__ so_w,
                            const float* __restrict__ aw_w,
                            const float* __restrict__ vp_w,
                            const float* __restrict__ op_w,
                            const float* __restrict__ w1,
                            const float* __restrict__ w2,
                            const float* __restrict__ so_b,
                            const float* __restrict__ aw_b,
                            const float* __restrict__ qmask,
                            ushort* __restrict__ out,
                            float* __restrict__ bias_out,
                            float* __restrict__ cum_y,
                            float* __restrict__ cum_x) {
    int i = blockIdx.x * 256 + threadIdx.x;
    if (i < WTOT) {
        float v;
        int j = i;
        if (j < SOW_N) v = so_w[j];
        else if ((j -= SOW_N) < AWW_N) v = aw_w[j];
        else if ((j -= AWW_N) < VPW_N) v = vp_w[j];
        else if ((j -= VPW_N) < OPW_N) v = op_w[j];
        else if ((j -= OPW_N) < W1_N)  v = w1[j];
        else { j -= W1_N; v = w2[j]; }
        out[i] = f2bf(v);
        return;
    }
    int j = i - WTOT;
    if (j < 324) { bias_out[j] = (j < 216) ? so_b[j] : aw_b[j - 216]; return; }
    int t = j - 324;
    if (t < Bc * Wc) {
        int b = t / Wc, w = t % Wc;
        float run = 0.f;
        for (int h = 0; h < Hc; ++h) {
            run += (qmask[(b * Hc + h) * Wc + w] == 255.0f) ? 0.f : 1.f;
            cum_y[(b * Hc + h) * Wc + w] = run;
        }
    } else if (t < Bc * Wc + Bc * Hc) {
        int t2 = t - Bc * Wc;
        int b = t2 / Hc, h = t2 % Hc;
        float run = 0.f;
        for (int w = 0; w < Wc; ++w) {
            run += (qmask[(b * Hc + h) * Wc + w] == 255.0f) ? 0.f : 1.f;
            cum_x[(b * Hc + h) * Wc + w] = run;
        }
    }
}

// ---------------------------------------------------------------------------
// K1: transpose x[B,D,N] -> src_f[B,N,D] (fp32) + src_bf (bf16);
//     qpos_bf = bf16(src + sine_pos + level_embed). Fast-math trig.
// ---------------------------------------------------------------------------
__global__ void transpose_pos_kernel(const float* __restrict__ x,
                                     const float* __restrict__ cum_y,
                                     const float* __restrict__ cum_x,
                                     const float* __restrict__ level_embed,
                                     float* __restrict__ src_f,
                                     ushort* __restrict__ src_bf,
                                     ushort* __restrict__ qpos_bf) {
    __shared__ float tile[32][33];
    int b  = blockIdx.z;
    int n0 = blockIdx.x * 32, d0 = blockIdx.y * 32;
    int tx = threadIdx.x, ty = threadIdx.y;
    tile[ty][tx] = x[((size_t)b * Dc + (d0 + ty)) * Nc + (n0 + tx)];
    __syncthreads();
    int n = n0 + ty, d = d0 + tx;
    float v = tile[tx][ty];
    size_t oi = ((size_t)b * Nc + n) * Dc + d;
    src_f[oi]  = v;
    src_bf[oi] = f2bf(v);
    int h = n >> 6, w = n & 63;
    const float TWO_PI = 6.28318530717958647692f;
    float vy = cum_y[(b * Hc + h) * Wc + w] /
               (cum_y[(b * Hc + (Hc - 1)) * Wc + w] + 1e-6f) * TWO_PI;
    float vx = cum_x[(b * Hc + h) * Wc + w] /
               (cum_x[(b * Hc + h) * Wc + (Wc - 1)] + 1e-6f) * TWO_PI;
    int   i  = (d < 192) ? d : d - 192;
    float vv = (d < 192) ? vy : vx;
    float e   = (float)(i >> 1) * (2.0f / 192.0f);
    float idt = exp2f(e * -13.28771237954945f);
    float ang = vv * idt;
    float pe  = (i & 1) ? __cosf(ang) : __sinf(ang);
    qpos_bf[oi] = f2bf(v + pe + level_embed[d]);
}

// ---------------------------------------------------------------------------
// K2: hybrid bf16 MFMA GEMM v6.
//     C[16384,Nout] = A[16384,K] * Wt[Nout,K]^T (+bias)(+relu)(+rowmask)
//     B (64-col tile) staged in LDS fragment-major via global_load_lds,
//     K-chunks of 96, double-buffered, next chunk prefetched before compute
//     (barrier drain overlaps 48 MFMAs). A loaded direct to registers
//     (16B frags, L1/L2-served). Block: 4 waves x (64r x 64c) = 256x64 tile.
// ---------------------------------------------------------------------------
template <int KT>
__global__ __launch_bounds__(256) void gemm_v6_kernel(
        const ushort* __restrict__ A, const ushort* __restrict__ Wt,
        const float* __restrict__ bias,
        float* __restrict__ Cf, ushort* __restrict__ Cb,
        int Nout, int relu, const float* __restrict__ qmask) {
    constexpr int KCH = 96;
    constexpr int NCH = KT / KCH;
    // Bs[buf][k16][col][8]: k16 in 0..11 (8 ushorts of K each), col 0..63
    __shared__ ushort Bs[2][12 * 64 * 8];   // 2 x 12KB
    const int tid  = threadIdx.x;
    const int lane = tid & 63;
    const int wv   = tid >> 6;
    const int quad = lane >> 4;
    const int lrow = lane & 15;
    const int n0   = blockIdx.x * 64;
    const int m0   = blockIdx.y * 256 + wv * 64;

    // B staging: wave wv stages k16 = wv*3+s; lane -> col. LDS dest is
    // wave-uniform base + lane*16 (linear16 = k16*64 + col).  Global addr:
    // Wt[(n0+col)*KT + kc + k16*8] — strided, L2-resident weights.
    const ushort* wt_lane = Wt + (size_t)(n0 + lane) * KT + wv * 24;

    floatx4 acc[4][4];
    #pragma unroll
    for (int i = 0; i < 4; ++i)
        #pragma unroll
        for (int j = 0; j < 4; ++j)
            acc[i][j] = (floatx4)(0.f);

    const ushort* Ab = A + (size_t)(m0 + lrow) * KT + quad * 8;

    // prologue: stage chunk 0 into buf 0
    {
        ushort* lb = &Bs[0][(wv * 3) * 512];
        #pragma unroll
        for (int s = 0; s < 3; ++s)
            gload_lds16(wt_lane + s * 8, lb + s * 512);
    }
    __syncthreads();

    for (int c = 0; c < NCH; ++c) {
        if (c + 1 < NCH) {
            ushort* lb = &Bs[(c + 1) & 1][(wv * 3) * 512];
            const ushort* gb = wt_lane + (c + 1) * KCH;
            #pragma unroll
            for (int s = 0; s < 3; ++s)
                gload_lds16(gb + s * 8, lb + s * 512);
        }
        const ushort* bsrc = &Bs[c & 1][0];
        #pragma unroll
        for (int kk = 0; kk < 3; ++kk) {
            const int k = c * KCH + kk * 32;
            short8 afr[4], bfr[4];
            #pragma unroll
            for (int i = 0; i < 4; ++i)
                afr[i] = *(const short8*)(Ab + (size_t)(i * 16) * KT + k);
            #pragma unroll
            for (int j = 0; j < 4; ++j)
                bfr[j] = *(const short8*)(bsrc +
                          ((kk * 4 + quad) * 64 + j * 16 + lrow) * 8);
            #pragma unroll
            for (int i = 0; i < 4; ++i)
                #pragma unroll
                for (int j = 0; j < 4; ++j)
                    acc[i][j] = __builtin_amdgcn_mfma_f32_16x16x32_bf16(
                        afr[i], bfr[j], acc[i][j], 0, 0, 0);
        }
        __syncthreads();
    }

    // row-mask multipliers (value projection only)
    float mz[4][4];
    #pragma unroll
    for (int i = 0; i < 4; ++i)
        #pragma unroll
        for (int r = 0; r < 4; ++r) {
            int row = m0 + i * 16 + quad * 4 + r;
            mz[i][r] = (qmask && qmask[row] == 255.0f) ? 0.f : 1.f;
        }

    // C/D layout (16x16x32): col = lane&15, row = quad*4 + reg
    #pragma unroll
    for (int j = 0; j < 4; ++j) {
        int col = n0 + j * 16 + lrow;
        if (col >= Nout) continue;
        float bsv = bias ? bias[col] : 0.f;
        #pragma unroll
        for (int i = 0; i < 4; ++i) {
            #pragma unroll
            for (int r = 0; r < 4; ++r) {
                int row = m0 + i * 16 + quad * 4 + r;
                float v = acc[i][j][r] + bsv;
                if (relu) v = fmaxf(v, 0.f);
                v *= mz[i][r];
                if (Cf) Cf[(size_t)row * Nout + col] = v;
                if (Cb) Cb[(size_t)row * Nout + col] = f2bf(v);
            }
        }
    }
}

// ---------------------------------------------------------------------------
// K4: deformable attention gather v4 (softmax fused).
//     4-lane group per (b,n,m); lane = 8 channels (bf16x8 = 16B loads).
// ---------------------------------------------------------------------------
__global__ __launch_bounds__(256) void deform_attn_kernel(
        const ushort* __restrict__ value_bf, const float* __restrict__ soaw,
        ushort* __restrict__ out) {
    int gid = blockIdx.x * 64 + (threadIdx.x >> 2);   // (b*N+n)*M + m
    int l4  = threadIdx.x & 3;                        // channel octet
    int m  = gid % Mc;
    int bn = gid / Mc;
    int b  = bn >> 12;
    int n  = bn & 4095;
    int h  = n >> 6, w = n & 63;
    const float* sop = soaw + (size_t)bn * 324 + m * 18;
    const float* lgt = soaw + (size_t)bn * 324 + 216 + m * Pc;
    // softmax over 9 logits (redundant across the 4 lanes of the group)
    float awv[Pc];
    float mx = lgt[0];
    #pragma unroll
    for (int i = 1; i < Pc; ++i) mx = fmaxf(mx, lgt[i]);
    float ssum = 0.f;
    #pragma unroll
    for (int i = 0; i < Pc; ++i) { awv[i] = __expf(lgt[i] - mx); ssum += awv[i]; }
    float sinv = 1.f / ssum;
    const ushort* vb = value_bf + ((size_t)b * Nc) * Dc + m * DHc + l4 * 8;
    float acc[8] = {0.f, 0.f, 0.f, 0.f, 0.f, 0.f, 0.f, 0.f};
    #pragma unroll
    for (int p = 0; p < Pc; ++p) {
        float2 so2 = *(const float2*)(sop + p * 2);
        float px = (float)w + so2.x;     // (ref + so/64)*64 - 0.5 simplifies
        float py = (float)h + so2.y;
        float x0f = floorf(px), y0f = floorf(py);
        float lx = px - x0f, ly = py - y0f;
        int x0 = (int)x0f, y0 = (int)y0f;
        int x1 = x0 + 1,  y1 = y0 + 1;
        float a = awv[p] * sinv;
        float w00 = (1.f - lx) * (1.f - ly) * a;
        float w01 = lx * (1.f - ly) * a;
        float w10 = (1.f - lx) * ly * a;
        float w11 = lx * ly * a;
        bool bx0 = (unsigned)x0 < 64u, bx1 = (unsigned)x1 < 64u;
        bool by0 = (unsigned)y0 < 64u, by1 = (unsigned)y1 < 64u;
        w00 = (bx0 && by0) ? w00 : 0.f;
        w01 = (bx1 && by0) ? w01 : 0.f;
        w10 = (bx0 && by1) ? w10 : 0.f;
        w11 = (bx1 && by1) ? w11 : 0.f;
        int cx0 = min(max(x0, 0), 63), cx1 = min(max(x1, 0), 63);
        int cy0 = min(max(y0, 0), 63), cy1 = min(max(y1, 0), 63);
        uint4 q00 = *(const uint4*)(vb + (size_t)(cy0 * 64 + cx0) * Dc);
        uint4 q01 = *(const uint4*)(vb + (size_t)(cy0 * 64 + cx1) * Dc);
        uint4 q10 = *(const uint4*)(vb + (size_t)(cy1 * 64 + cx0) * Dc);
        uint4 q11 = *(const uint4*)(vb + (size_t)(cy1 * 64 + cx1) * Dc);
        union { unsigned u; float f; } t;
        #define ACC2(word, wg, k)                                   \
            t.u = (word) << 16;         acc[k]     += (wg) * t.f;   \
            t.u = (word) & 0xffff0000u; acc[k + 1] += (wg) * t.f;
        #define ACC8(q, wg) \
            ACC2((q).x, wg, 0) ACC2((q).y, wg, 2) ACC2((q).z, wg, 4) ACC2((q).w, wg, 6)
        ACC8(q00, w00) ACC8(q01, w01) ACC8(q10, w10) ACC8(q11, w11)
        #undef ACC8
        #undef ACC2
    }
    short8 o;
    #pragma unroll
    for (int k = 0; k < 8; ++k) o[k] = (short)f2bf(acc[k]);
    *(short8*)(out + (size_t)bn * Dc + m * DHc + l4 * 8) = o;
}

// ---------------------------------------------------------------------------
// K5: out = LayerNorm(a + r) * g + beta ; optional bf16 copy. In-place safe.
// ---------------------------------------------------------------------------
__global__ __launch_bounds__(128) void ln_residual_kernel(
        const float* a, const float* r,
        const float* g, const float* beta,
        float* out, ushort* outb) {
    int row = blockIdx.x;
    int tid = threadIdx.x;
    float4 v = make_float4(0.f, 0.f, 0.f, 0.f);
    if (tid < 96) {
        float4 av = ((const float4*)(a + (size_t)row * Dc))[tid];
        float4 rv = ((const float4*)(r + (size_t)row * Dc))[tid];
        v.x = av.x + rv.x; v.y = av.y + rv.y;
        v.z = av.z + rv.z; v.w = av.w + rv.w;
    }
    float s1 = v.x + v.y + v.z + v.w;
    float s2 = v.x * v.x + v.y * v.y + v.z * v.z + v.w * v.w;
    __shared__ float sh1[128], sh2[128];
    sh1[tid] = s1; sh2[tid] = s2;
    __syncthreads();
    for (int off = 64; off > 0; off >>= 1) {
        if (tid < off) { sh1[tid] += sh1[tid + off]; sh2[tid] += sh2[tid + off]; }
        __syncthreads();
    }
    float mu  = sh1[0] * (1.0f / Dc);
    float var = sh2[0] * (1.0f / Dc) - mu * mu;
    float rs  = rsqrtf(var + 1e-5f);
    if (tid < 96) {
        float4 gv = ((const float4*)g)[tid];
        float4 bv = ((const float4*)beta)[tid];
        float4 o;
        o.x = (v.x - mu) * rs * gv.x + bv.x;
        o.y = (v.y - mu) * rs * gv.y + bv.y;
        o.z = (v.z - mu) * rs * gv.z + bv.z;
        o.w = (v.w - mu) * rs * gv.w + bv.w;
        ((float4*)(out + (size_t)row * Dc))[tid] = o;
        if (outb) {
            ushort4 ob;
            ob.x = f2bf(o.x); ob.y = f2bf(o.y);
            ob.z = f2bf(o.z); ob.w = f2bf(o.w);
            ((ushort4*)(outb + (size_t)row * Dc))[tid] = ob;
        }
    }
}

// ---------------------------------------------------------------------------
// K6: transpose src[B,N,D] -> out[B,D,N]
// ---------------------------------------------------------------------------
__global__ void transpose_out_kernel(const float* __restrict__ src,
                                     float* __restrict__ out) {
    __shared__ float tile[32][33];
    int b  = blockIdx.z;
    int n0 = blockIdx.x * 32, d0 = blockIdx.y * 32;
    int tx = threadIdx.x, ty = threadIdx.y;
    tile[ty][tx] = src[((size_t)b * Nc + (n0 + ty)) * Dc + (d0 + tx)];
    __syncthreads();
    out[((size_t)b * Dc + (d0 + ty)) * Nc + (n0 + tx)] = tile[tx][ty];
}

// ---------------------------------------------------------------------------
extern "C" void kernel_launch(void* const* d_in, const int* in_sizes, int n_in,
                              void* d_out, int out_size, void* d_ws, size_t ws_size,
                              hipStream_t stream) {
    (void)in_sizes; (void)n_in; (void)out_size; (void)ws_size;
    const float* x      = (const float*)d_in[0];
    const float* qmask  = (const float*)d_in[1];
    const float* so_w   = (const float*)d_in[2];
    const float* so_b   = (const float*)d_in[3];
    const float* aw_w   = (const float*)d_in[4];
    const float* aw_b   = (const float*)d_in[5];
    const float* vp_w   = (const float*)d_in[6];
    const float* vp_b   = (const float*)d_in[7];
    const float* op_w   = (const float*)d_in[8];
    const float* op_b   = (const float*)d_in[9];
    const float* ln1_g  = (const float*)d_in[10];
    const float* ln1_b  = (const float*)d_in[11];
    const float* w1     = (const float*)d_in[12];
    const float* w2     = (const float*)d_in[13];
    const float* ln2_g  = (const float*)d_in[14];
    const float* ln2_b  = (const float*)d_in[15];
    const float* lvl    = (const float*)d_in[16];
    float* out = (float*)d_out;

    // Workspace layout (~120 MB in floats):
    float*  ws       = (float*)d_ws;
    float*  src_f    = ws;                          // 6291456 f (residual/q1/q2)
    float*  proj_f   = src_f + 6291456;             // 6291456 f (op out, FFN2 out)
    ushort* src_bf   = (ushort*)(proj_f + 6291456); // 6291456 us
    ushort* qpos_bf  = src_bf + 6291456;            // 6291456 us (qpos->attn->q1_bf)
    ushort* value_bf = qpos_bf + 6291456;           // 6291456 us
    ushort* hbuf_bf  = value_bf + 6291456;          // 18874368 us (FFN hidden)
    float*  soaw_f   = (float*)hbuf_bf;             // 5308416 f overlay (dead pre-FFN1)
    ushort* wbuf     = hbuf_bf + 18874368;          // 1304064 us
    float*  soaw_bias= (float*)(wbuf + 1304064);    // 324 f
    float*  cum_y    = soaw_bias + 324;             // 16384 f
    float*  cum_x    = cum_y + 16384;               // 16384 f

    const ushort* soaw_wb = wbuf;                   // [324,384] (so_w ++ aw_w)
    const ushort* vp_wb = soaw_wb + SOW_N + AWW_N;
    const ushort* op_wb = vp_wb + VPW_N;
    const ushort* w1_b  = op_wb + OPW_N;
    const ushort* w2_b  = w1_b + W1_N;

    // 0) fused init: weight convert + bias concat + mask cumsums
    init_kernel<<<(WTOT + 324 + 512 + 255) / 256, 256, 0, stream>>>(
        so_w, aw_w, vp_w, op_w, w1, w2, so_b, aw_b, qmask,
        wbuf, soaw_bias, cum_y, cum_x);
    // 1) transpose + pos encode
    transpose_pos_kernel<<<dim3(Nc / 32, Dc / 32, Bc), dim3(32, 32), 0, stream>>>(
        x, cum_y, cum_x, lvl, src_f, src_bf, qpos_bf);
    // 2) merged sampling-offset + attn-weight projection; value projection
    gemm_v6_kernel<384><<<dim3(6, BNc / 256), 256, 0, stream>>>(
        qpos_bf, soaw_wb, soaw_bias, soaw_f, nullptr, 324, 0, nullptr);
    gemm_v6_kernel<384><<<dim3(6, BNc / 256), 256, 0, stream>>>(
        src_bf, vp_wb, vp_b, nullptr, value_bf, Dc, 0, qmask);
    // 3) deformable gather (softmax fused) -> attn_bf (into qpos_bf; qpos dead)
    deform_attn_kernel<<<(BNc * Mc) / 64, 256, 0, stream>>>(
        value_bf, soaw_f, qpos_bf);
    // 4) output projection
    gemm_v6_kernel<384><<<dim3(6, BNc / 256), 256, 0, stream>>>(
        qpos_bf, op_wb, op_b, proj_f, nullptr, Dc, 0, nullptr);
    // 5) q1 = LN(src + attnproj) — in place, bf16 copy to qpos_bf
    ln_residual_kernel<<<BNc, 128, 0, stream>>>(
        src_f, proj_f, ln1_g, ln1_b, src_f, qpos_bf);
    // 6) FFN
    gemm_v6_kernel<384><<<dim3(18, BNc / 256), 256, 0, stream>>>(
        qpos_bf, w1_b, nullptr, nullptr, hbuf_bf, DFFc, 1, nullptr);
    gemm_v6_kernel<1152><<<dim3(6, BNc / 256), 256, 0, stream>>>(
        hbuf_bf, w2_b, nullptr, proj_f, nullptr, Dc, 0, nullptr);
    // 7) q2 = LN(q1 + ffn2) — in place
    ln_residual_kernel<<<BNc, 128, 0, stream>>>(
        src_f, proj_f, ln2_g, ln2_b, src_f, nullptr);
    // 8) transpose to [B,D,H,W]
    transpose_out_kernel<<<dim3(Nc / 32, Dc / 32, Bc), dim3(32, 32), 0, stream>>>(
        src_f, out);
}